// Round 12
// baseline (84.025 us; speedup 1.0000x reference)
//
#include <hip/hip_runtime.h>

#define BB 32
#define SS 512
#define FF 256
#define NN 8

#define L1 8                // chunk length
#define NCH 64              // SS/L1
#define CG1 8               // channels per block (kernel 1)
#define NT1 512             // threads (kernel 1) = NCH*CG1
#define XST 9               // xs row stride words
#define VST 68              // vs row stride words (16B-aligned)

// ---------------- kernel 1: incoming state of every chunk -> ws ----------------
// ws[b][j][f][n] = state entering chunk j for channel (b,f); ws[b][0][*] = 0.
__global__ __launch_bounds__(NT1) void hippo_states8(
    const float* __restrict__ x,
    const float* __restrict__ Ad,
    const float* __restrict__ Bd,
    float* __restrict__ ws)
{
    __shared__ __align__(16) float xs[SS * XST];          // 18432 B
    __shared__ __align__(16) float vs[NCH * VST];         // 17408 B
    __shared__ __align__(16) float pw[6][64];             // M^(8*2^k), k=0..5
    __shared__ __align__(16) float Mp[3][64];             // M^1,2,4
    __shared__ __align__(16) float Ks[L1][NN];            // K[i] = M^(7-i) B

    const int tid = threadIdx.x;
    const int b   = blockIdx.x >> 5;          // 32 f-groups per batch
    const int f0  = (blockIdx.x & 31) * CG1;

    // ---- wave 0: matrix algebra || waves 1-7: stage x tile (coalesced) ----
    if (tid < 64) {
        const int m = tid >> 3, n = tid & 7;
        Mp[0][tid] = Ad[n * NN + m];                      // M = A^T
#pragma unroll
        for (int s = 1; s < 3; ++s) {                     // M^2, M^4
            float a = 0.f;
#pragma unroll
            for (int t = 0; t < 8; ++t) a = fmaf(Mp[s-1][m*8+t], Mp[s-1][t*8+n], a);
            Mp[s][tid] = a;
        }
        {   float a = 0.f;                                // M^8
#pragma unroll
            for (int t = 0; t < 8; ++t) a = fmaf(Mp[2][m*8+t], Mp[2][t*8+n], a);
            pw[0][tid] = a; }
#pragma unroll
        for (int k = 1; k < 6; ++k) {                     // M^16 .. M^256
            float a = 0.f;
#pragma unroll
            for (int t = 0; t < 8; ++t) a = fmaf(pw[k-1][m*8+t], pw[k-1][t*8+n], a);
            pw[k][tid] = a;
        }
        if (tid < L1) {                                   // K[i] = M^(7-i) B
            const int e = L1 - 1 - tid;                   // 0..7, 3 bits
            float v[8];
#pragma unroll
            for (int q = 0; q < 8; ++q) v[q] = Bd[q];
#pragma unroll
            for (int s = 0; s < 3; ++s) {
                if (e & (1 << s)) {
                    float nv[8];
#pragma unroll
                    for (int r = 0; r < 8; ++r) {
                        float a = 0.f;
#pragma unroll
                        for (int c2 = 0; c2 < 8; ++c2)
                            a = fmaf(Mp[s][r * 8 + c2], v[c2], a);
                        nv[r] = a;
                    }
#pragma unroll
                    for (int r = 0; r < 8; ++r) v[r] = nv[r];
                }
            }
#pragma unroll
            for (int r = 0; r < 8; ++r) Ks[tid][r] = v[r];
        }
    } else {
        const float* xb = x + (size_t)b * SS * FF + f0;
#pragma unroll
        for (int k = 0; k < 3; ++k) {
            const int i2 = (tid - 64) + k * 448;          // need 0..1023
            if (i2 < 1024) {
                const int t = i2 >> 1, q = i2 & 1;
                float4 v = *(const float4*)(xb + (size_t)t * FF + q * 4);
                float* d = &xs[t * XST + q * 4];
                d[0] = v.x; d[1] = v.y; d[2] = v.z; d[3] = v.w;
            }
        }
    }
    __syncthreads();

    // ---- phase 1: chunk-end state from zero (Krylov, 8 FMA/step) ----
    const int j  = tid >> 3;             // chunk 0..63
    const int ch = tid & 7;
    {
        const int t0 = j * L1;
        float c[NN];
#pragma unroll
        for (int m = 0; m < NN; ++m) c[m] = 0.f;
#pragma unroll
        for (int i = 0; i < L1; ++i) {
            const float xt = xs[(t0 + i) * XST + ch];
            const float4 k0 = *(const float4*)&Ks[i][0];
            const float4 k1 = *(const float4*)&Ks[i][4];
            c[0] = fmaf(k0.x, xt, c[0]); c[1] = fmaf(k0.y, xt, c[1]);
            c[2] = fmaf(k0.z, xt, c[2]); c[3] = fmaf(k0.w, xt, c[3]);
            c[4] = fmaf(k1.x, xt, c[4]); c[5] = fmaf(k1.y, xt, c[5]);
            c[6] = fmaf(k1.z, xt, c[6]); c[7] = fmaf(k1.w, xt, c[7]);
        }
        float* vj = &vs[j * VST + ch * NN];
        *(float4*)(vj)     = make_float4(c[0], c[1], c[2], c[3]);
        *(float4*)(vj + 4) = make_float4(c[4], c[5], c[6], c[7]);
    }
    __syncthreads();

    // ---- phase 2: in-wave shfl scan over 64 chunks; wave w = channel w ----
    {
        const int w  = tid >> 6;          // channel-in-block
        const int js = tid & 63;          // chunk = lane

        float s[NN];
        {
            const float* vp = &vs[js * VST + w * NN];
            float4 p0 = *(const float4*)(vp);
            float4 p1 = *(const float4*)(vp + 4);
            s[0] = p0.x; s[1] = p0.y; s[2] = p0.z; s[3] = p0.w;
            s[4] = p1.x; s[5] = p1.y; s[6] = p1.z; s[7] = p1.w;
        }
#pragma unroll
        for (int k = 0; k < 6; ++k) {
            const int d = 1 << k;
            float prev[NN];
#pragma unroll
            for (int m = 0; m < NN; ++m) prev[m] = __shfl_up(s[m], d, 64);
            if (js >= d) {
#pragma unroll
                for (int m = 0; m < NN; ++m) {
                    const float4 r0 = *(const float4*)&pw[k][m * 8];
                    const float4 r1 = *(const float4*)&pw[k][m * 8 + 4];
                    float a = s[m];
                    a = fmaf(r0.x, prev[0], a); a = fmaf(r0.y, prev[1], a);
                    a = fmaf(r0.z, prev[2], a); a = fmaf(r0.w, prev[3], a);
                    a = fmaf(r1.x, prev[4], a); a = fmaf(r1.y, prev[5], a);
                    a = fmaf(r1.z, prev[6], a); a = fmaf(r1.w, prev[7], a);
                    s[m] = a;
                }
            }
        }
        // inclusive state of chunk js = incoming state of chunk js+1
        if (js < NCH - 1) {
            float4* w4 = (float4*)(ws + (((size_t)b * NCH + js + 1) * FF + f0 + w) * NN);
            w4[0] = make_float4(s[0], s[1], s[2], s[3]);
            w4[1] = make_float4(s[4], s[5], s[6], s[7]);
        } else {
            float4* w4 = (float4*)(ws + (((size_t)b * NCH + 0) * FF + f0 + w) * NN);
            w4[0] = make_float4(0.f, 0.f, 0.f, 0.f);
            w4[1] = make_float4(0.f, 0.f, 0.f, 0.f);
        }
    }
}

// ---------------- kernel 2: wave-per-row emit, fully sequential stores ----------------
// wave-unit u = (b, j); lane owns channels 4*lane..4*lane+3 (16-float state in VGPRs).
// Per step: dense 1KB x-load, 288 FMA, 8 stores walking the 8KB row end-to-end.
__global__ __launch_bounds__(256) void hippo_emit_seq(
    const float* __restrict__ x,
    const float* __restrict__ Ad,
    const float* __restrict__ Bd,
    const float* __restrict__ ws,
    float* __restrict__ out)
{
    const int tid  = threadIdx.x;
    const int lane = tid & 63;
    const int u    = blockIdx.x * 4 + (tid >> 6);   // 2048 wave-units
    const int b    = u >> 6;
    const int j    = u & 63;

    // thread-uniform A (row-major [n][m]) and B -> scalar regs
    float As[NN * NN];
#pragma unroll
    for (int i = 0; i < NN * NN; ++i) As[i] = Ad[i];
    float Bv[NN];
#pragma unroll
    for (int m = 0; m < NN; ++m) Bv[m] = Bd[m];

    // incoming state for 4 channels (32 floats, contiguous 128B per lane)
    float c[4][NN];
    {
        const float* wp = ws + (((size_t)b * NCH + j) * FF + 4 * lane) * NN;
#pragma unroll
        for (int cc = 0; cc < 4; ++cc) {
            float4 a0 = *(const float4*)(wp + cc * NN);
            float4 a1 = *(const float4*)(wp + cc * NN + 4);
            c[cc][0] = a0.x; c[cc][1] = a0.y; c[cc][2] = a0.z; c[cc][3] = a0.w;
            c[cc][4] = a1.x; c[cc][5] = a1.y; c[cc][6] = a1.z; c[cc][7] = a1.w;
        }
    }

    const float* xp = x + ((size_t)b * SS + j * L1) * FF + 4 * lane;
    float* op = out + (((size_t)b * SS + j * L1) * FF + 4 * lane) * NN;

    float4 xv = *(const float4*)(xp);
#pragma unroll
    for (int t = 0; t < L1; ++t) {
        float4 xn = xv;
        if (t + 1 < L1) xn = *(const float4*)(xp + (size_t)(t + 1) * FF);

        float* ob = op + (size_t)t * (FF * NN);
#pragma unroll
        for (int cc = 0; cc < 4; ++cc) {
            const float xc = ((const float*)&xv)[cc];
            float nc[NN];
#pragma unroll
            for (int m = 0; m < NN; ++m) {
                float a = Bv[m] * xc;
#pragma unroll
                for (int n = 0; n < NN; ++n) a = fmaf(As[n * NN + m], c[cc][n], a);
                nc[m] = a;
            }
#pragma unroll
            for (int m = 0; m < NN; ++m) c[cc][m] = nc[m];

            float4* o4 = (float4*)(ob + cc * NN);
            o4[0] = make_float4(nc[0], nc[1], nc[2], nc[3]);
            o4[1] = make_float4(nc[4], nc[5], nc[6], nc[7]);
        }
        xv = xn;
    }
}

extern "C" void kernel_launch(void* const* d_in, const int* in_sizes, int n_in,
                              void* d_out, int out_size, void* d_ws, size_t ws_size,
                              hipStream_t stream) {
    const float* x  = (const float*)d_in[0];
    const float* Ad = (const float*)d_in[1];
    const float* Bd = (const float*)d_in[2];
    float* out = (float*)d_out;
    float* ws  = (float*)d_ws;   // BB*NCH*FF*NN*4 = 16 MiB

    const int grid1 = BB * (FF / CG1);     // 1024 blocks x 512 threads
    hipLaunchKernelGGL(hippo_states8, dim3(grid1), dim3(NT1), 0, stream,
                       x, Ad, Bd, ws);

    const int grid2 = (BB * NCH) / 4;      // 512 blocks x 256 threads
    hipLaunchKernelGGL(hippo_emit_seq, dim3(grid2), dim3(256), 0, stream,
                       x, Ad, Bd, ws, out);
}

// Round 14
// 38.904 us; speedup vs baseline: 2.1598x; 2.1598x over previous
//
#include <hip/hip_runtime.h>

#define BB 32
#define SS 512
#define FF 256
#define NN 8
#define L1 8                // chunk length
#define NCH 64              // SS/L1
#define CGF 8               // channels per block
#define NTF 512             // threads = NCH*CGF
#define XST 9               // xs base row stride (words)
#define VST 68              // vs row stride (words): >=64 payload, 16B-aligned

// skewed xs index: j-groups (t0=8j) land on distinct banks
__device__ __forceinline__ int xsidx(int t, int c) {
    return t * XST + (t >> 3) + c;
}

__global__ __launch_bounds__(NTF, 8) void hippo_fused5(
    const float* __restrict__ x,
    const float* __restrict__ Ad,
    const float* __restrict__ Bd,
    float* __restrict__ out)
{
    __shared__ __align__(16) float xs[SS * XST + NCH + 8];   // ~18.7 KB
    __shared__ __align__(16) float vs[NCH * VST];            // 17.4 KB
    __shared__ __align__(16) float pw[6][64];                // M^(8*2^k), k=0..5
    __shared__ __align__(16) float Mp[3][64];                // M^1,2,4
    __shared__ __align__(16) float Ks[L1][NN];               // K[i] = M^(7-i) B

    const int tid = threadIdx.x;

    // XCD-chunked swizzle
    const int h  = blockIdx.x;
    const int g  = (h & 7) * 128 + (h >> 3);
    const int b  = g >> 5;
    const int f0 = (g & 31) * CGF;

    // ---- wave 0: matrix algebra || waves 1-7: stage x tile ----
    if (tid < 64) {
        const int m = tid >> 3, n = tid & 7;
        Mp[0][tid] = Ad[n * NN + m];                      // M = A^T
#pragma unroll
        for (int s = 1; s < 3; ++s) {                     // M^2, M^4
            float a = 0.f;
#pragma unroll
            for (int t = 0; t < 8; ++t) a = fmaf(Mp[s-1][m*8+t], Mp[s-1][t*8+n], a);
            Mp[s][tid] = a;
        }
        {   float a = 0.f;                                // M^8
#pragma unroll
            for (int t = 0; t < 8; ++t) a = fmaf(Mp[2][m*8+t], Mp[2][t*8+n], a);
            pw[0][tid] = a; }
#pragma unroll
        for (int k = 1; k < 6; ++k) {                     // M^16 .. M^256
            float a = 0.f;
#pragma unroll
            for (int t = 0; t < 8; ++t) a = fmaf(pw[k-1][m*8+t], pw[k-1][t*8+n], a);
            pw[k][tid] = a;
        }
        if (tid < L1) {                                   // K[i] = M^(7-i) B
            const int e = L1 - 1 - tid;                   // 3 bits
            float v[8];
#pragma unroll
            for (int q = 0; q < 8; ++q) v[q] = Bd[q];
#pragma unroll
            for (int s = 0; s < 3; ++s) {
                if (e & (1 << s)) {
                    float nv[8];
#pragma unroll
                    for (int r = 0; r < 8; ++r) {
                        float a = 0.f;
#pragma unroll
                        for (int c2 = 0; c2 < 8; ++c2)
                            a = fmaf(Mp[s][r * 8 + c2], v[c2], a);
                        nv[r] = a;
                    }
#pragma unroll
                    for (int r = 0; r < 8; ++r) v[r] = nv[r];
                }
            }
#pragma unroll
            for (int r = 0; r < 8; ++r) Ks[tid][r] = v[r];
        }
    } else {
        const float* xb = x + (size_t)b * SS * FF + f0;
#pragma unroll
        for (int k = 0; k < 3; ++k) {
            const int i2 = (tid - 64) + k * 448;          // need 0..1023
            if (i2 < 1024) {
                const int t = i2 >> 1, q = i2 & 1;
                float4 v = *(const float4*)(xb + (size_t)t * FF + q * 4);
                float* d = &xs[xsidx(t, q * 4)];
                d[0] = v.x; d[1] = v.y; d[2] = v.z; d[3] = v.w;
            }
        }
    }

    // thread-uniform A/B -> scalar regs (for emit)
    float As[NN * NN];
#pragma unroll
    for (int i = 0; i < NN * NN; ++i) As[i] = Ad[i];
    float Bv[NN];
#pragma unroll
    for (int m = 0; m < NN; ++m) Bv[m] = Bd[m];

    __syncthreads();   // barrier 1: xs + algebra ready

    // ---- phase 1: chunk-end state from zero (Krylov, 8 FMA/step) ----
    const int j  = tid >> 3;            // chunk 0..63
    const int ch = tid & 7;
    const int t0 = j * L1;
    {
        float c[NN];
#pragma unroll
        for (int m = 0; m < NN; ++m) c[m] = 0.f;
#pragma unroll
        for (int i = 0; i < L1; ++i) {
            const float xt = xs[xsidx(t0 + i, ch)];
            const float4 k0 = *(const float4*)&Ks[i][0];
            const float4 k1 = *(const float4*)&Ks[i][4];
            c[0] = fmaf(k0.x, xt, c[0]); c[1] = fmaf(k0.y, xt, c[1]);
            c[2] = fmaf(k0.z, xt, c[2]); c[3] = fmaf(k0.w, xt, c[3]);
            c[4] = fmaf(k1.x, xt, c[4]); c[5] = fmaf(k1.y, xt, c[5]);
            c[6] = fmaf(k1.z, xt, c[6]); c[7] = fmaf(k1.w, xt, c[7]);
        }
        float* vj = &vs[j * VST + ch * NN];
        *(float4*)(vj)     = make_float4(c[0], c[1], c[2], c[3]);
        *(float4*)(vj + 4) = make_float4(c[4], c[5], c[6], c[7]);
    }
    __syncthreads();   // barrier 2: chunk-end states in vs

    // ---- phase 2: in-wave 64-lane scan; wave w = channel w, lane = chunk ----
    {
        const int w  = tid >> 6;          // channel 0..7
        const int js = tid & 63;          // chunk = lane

        float s[NN];
        {
            const float* vp = &vs[js * VST + w * NN];
            float4 p0 = *(const float4*)(vp);
            float4 p1 = *(const float4*)(vp + 4);
            s[0] = p0.x; s[1] = p0.y; s[2] = p0.z; s[3] = p0.w;
            s[4] = p1.x; s[5] = p1.y; s[6] = p1.z; s[7] = p1.w;
        }
#pragma unroll
        for (int k = 0; k < 6; ++k) {
            const int d = 1 << k;
            float prev[NN];
#pragma unroll
            for (int m = 0; m < NN; ++m) prev[m] = __shfl_up(s[m], d, 64);
            if (js >= d) {
#pragma unroll
                for (int m = 0; m < NN; ++m) {
                    const float4 r0 = *(const float4*)&pw[k][m * 8];
                    const float4 r1 = *(const float4*)&pw[k][m * 8 + 4];
                    float a = s[m];
                    a = fmaf(r0.x, prev[0], a); a = fmaf(r0.y, prev[1], a);
                    a = fmaf(r0.z, prev[2], a); a = fmaf(r0.w, prev[3], a);
                    a = fmaf(r1.x, prev[4], a); a = fmaf(r1.y, prev[5], a);
                    a = fmaf(r1.z, prev[6], a); a = fmaf(r1.w, prev[7], a);
                    s[m] = a;
                }
            }
        }
        float* vj = &vs[js * VST + w * NN];
        *(float4*)(vj)     = make_float4(s[0], s[1], s[2], s[3]);
        *(float4*)(vj + 4) = make_float4(s[4], s[5], s[6], s[7]);
    }
    __syncthreads();   // barrier 3: inclusive prefixes in vs

    // ---- phase 3: emit chunk j from incoming state (R8 store shape) ----
    float ci[NN];
    if (j > 0) {
        const float* vp = &vs[(j - 1) * VST + ch * NN];
        float4 p0 = *(const float4*)(vp);
        float4 p1 = *(const float4*)(vp + 4);
        ci[0] = p0.x; ci[1] = p0.y; ci[2] = p0.z; ci[3] = p0.w;
        ci[4] = p1.x; ci[5] = p1.y; ci[6] = p1.z; ci[7] = p1.w;
    } else {
#pragma unroll
        for (int m = 0; m < NN; ++m) ci[m] = 0.f;
    }

    float* op = out + (((size_t)b * SS + t0) * FF + f0 + ch) * NN;
#pragma unroll
    for (int i = 0; i < L1; ++i) {
        const float xt = xs[xsidx(t0 + i, ch)];
        float cn[NN];
#pragma unroll
        for (int m = 0; m < NN; ++m) {
            float a = Bv[m] * xt;
#pragma unroll
            for (int n = 0; n < NN; ++n) a = fmaf(As[n * NN + m], ci[n], a);
            cn[m] = a;
        }
#pragma unroll
        for (int m = 0; m < NN; ++m) ci[m] = cn[m];

        float4* o4 = (float4*)(op + (size_t)i * (FF * NN));
        o4[0] = make_float4(ci[0], ci[1], ci[2], ci[3]);
        o4[1] = make_float4(ci[4], ci[5], ci[6], ci[7]);
    }
}

extern "C" void kernel_launch(void* const* d_in, const int* in_sizes, int n_in,
                              void* d_out, int out_size, void* d_ws, size_t ws_size,
                              hipStream_t stream) {
    const float* x  = (const float*)d_in[0];
    const float* Ad = (const float*)d_in[1];
    const float* Bd = (const float*)d_in[2];
    float* out = (float*)d_out;

    const int grid = BB * (FF / CGF);   // 1024 blocks x 512 threads
    hipLaunchKernelGGL(hippo_fused5, dim3(grid), dim3(NTF), 0, stream,
                       x, Ad, Bd, out);
}